// Round 4
// baseline (385.477 us; speedup 1.0000x reference)
//
#include <hip/hip_runtime.h>
#include <hip/hip_bf16.h>

#define BB 32
#define TT 24
#define NN 325
#define DD 64
#define MROWS (BB * TT * NN)   // 249600 flat (b,t,n) rows
#define BNCNT (BB * NN)        // 10400 (b,n) problems
#define RSH 72                 // fallback: f16 LDS row stride (halves)
#define RSF 68                 // fallback: f32 LDS row stride (floats)
#define HS  76                 // ff kernel LDS stride (halves): 6lr-bank spread, 8B-aligned

typedef _Float16 h4 __attribute__((ext_vector_type(4)));
typedef _Float16 h2 __attribute__((ext_vector_type(2)));
typedef float    f4 __attribute__((ext_vector_type(4)));

// ---------------- prep: W (f32, [k][col]) -> Wt (f16, [col][k]) ----------------
__global__ void prep_w_kernel(const float* __restrict__ Wq, const float* __restrict__ Wk,
                              const float* __restrict__ Wv, const float* __restrict__ Wf1,
                              const float* __restrict__ Wf2, _Float16* __restrict__ Wt)
{
    __shared__ float tile[64][65];
    const float* W;
    switch (blockIdx.x) {
        case 0: W = Wq; break;
        case 1: W = Wk; break;
        case 2: W = Wv; break;
        case 3: W = Wf1; break;
        default: W = Wf2; break;
    }
    const int tid = threadIdx.x;
    const int g = tid >> 6, c = tid & 63;
    #pragma unroll
    for (int p = 0; p < 16; ++p) {
        const int row = p * 4 + g;
        tile[row][c] = W[row * 64 + c];
    }
    __syncthreads();
    _Float16* dst = Wt + blockIdx.x * 4096;
    #pragma unroll
    for (int p = 0; p < 16; ++p) {
        const int col = p * 4 + g;
        dst[col * 64 + c] = (_Float16)tile[c][col];  // Wt[col][k]
    }
}

__device__ inline float dot8(h4 qa, h4 qb, h4 ka, h4 kb) {
#if __has_builtin(__builtin_amdgcn_fdot2)
    h2 qa0 = {qa[0], qa[1]}, qa1 = {qa[2], qa[3]};
    h2 qb0 = {qb[0], qb[1]}, qb1 = {qb[2], qb[3]};
    h2 ka0 = {ka[0], ka[1]}, ka1 = {ka[2], ka[3]};
    h2 kb0 = {kb[0], kb[1]}, kb1 = {kb[2], kb[3]};
    float d = __builtin_amdgcn_fdot2(qa0, ka0, 0.f, false);
    d = __builtin_amdgcn_fdot2(qa1, ka1, d, false);
    d = __builtin_amdgcn_fdot2(qb0, kb0, d, false);
    d = __builtin_amdgcn_fdot2(qb1, kb1, d, false);
    return d;
#else
    return (float)qa[0]*(float)ka[0] + (float)qa[1]*(float)ka[1]
         + (float)qa[2]*(float)ka[2] + (float)qa[3]*(float)ka[3]
         + (float)qb[0]*(float)kb[0] + (float)qb[1]*(float)kb[1]
         + (float)qb[2]*(float)kb[2] + (float)qb[3]*(float)kb[3];
#endif
}

// ================= K1: QKV projection GEMM =================
// X [249600][64] f32 @ Wqkv -> QKV f16 laid out [bn][sep][t][64].
// Swapped-operand MFMA: mfma(Wfrag, Xfrag) => lane(lr,lg) holds
// out[row mbase+lr][cols 16nt+4lg+q], q=0..3  -> h4 store, f4 bias load.
__global__ __launch_bounds__(256) void qkv_kernel(
    const float* __restrict__ X, const _Float16* __restrict__ Wt,
    const float* __restrict__ bq, const float* __restrict__ bk,
    const float* __restrict__ bv, _Float16* __restrict__ QKV)
{
    const int lane = threadIdx.x & 63, w = threadIdx.x >> 6;
    const int lr = lane & 15, lg = lane >> 4;
    const int mbase = (blockIdx.x * 4 + w) * 16;
    const int m = mbase + lr;                 // < 249600 exactly (3900*4*16)

    h4 a[4];
    const float* xp = X + (size_t)m * DD;
    #pragma unroll
    for (int kt = 0; kt < 4; ++kt) {
        const f4 x = *(const f4*)(xp + kt * 16 + lg * 4);
        h4 h; h[0] = (_Float16)x[0]; h[1] = (_Float16)x[1];
        h[2] = (_Float16)x[2]; h[3] = (_Float16)x[3];
        a[kt] = h;
    }

    // m = (b*TT + t)*NN + n  ->  output row base in [bn][sep][t][64]
    const int b   = m / (TT * NN);
    const int rem = m - b * (TT * NN);
    const int t   = rem / NN;
    const int n   = rem - t * NN;
    const int bn  = b * NN + n;

    #pragma unroll
    for (int sep = 0; sep < 3; ++sep) {
        const float* bias = (sep == 0) ? bq : (sep == 1) ? bk : bv;
        const _Float16* wsep = Wt + sep * 4096;
        _Float16* osep = QKV + ((size_t)(bn * 3 + sep) * TT + t) * DD;
        #pragma unroll
        for (int nt = 0; nt < 4; ++nt) {
            h4 bfr[4];
            const _Float16* wp = wsep + (16 * nt + lr) * 64 + 4 * lg;
            #pragma unroll
            for (int kt = 0; kt < 4; ++kt) bfr[kt] = *(const h4*)(wp + 16 * kt);
            f4 acc = *(const f4*)(bias + 16 * nt + 4 * lg);
            #pragma unroll
            for (int kt = 0; kt < 4; ++kt)
                acc = __builtin_amdgcn_mfma_f32_16x16x16f16(bfr[kt], a[kt], acc, 0, 0, 0);
            h4 o;
            #pragma unroll
            for (int i = 0; i < 4; ++i) o[i] = (_Float16)fmaxf(acc[i], 0.f);
            *(h4*)(osep + 16 * nt + 4 * lg) = o;
        }
    }
}

// ================= K2: attention, one wave per (b,n), no LDS =================
__global__ __launch_bounds__(256) void attn_kernel(
    const _Float16* __restrict__ QKV, _Float16* __restrict__ ATT)
{
    const int lane = threadIdx.x & 63, w = threadIdx.x >> 6;
    const int bn = blockIdx.x * 4 + w;        // < 10400 exactly (2600*4)
    const int kh = lane & 7, tl = lane >> 3;

    const _Float16* qp = QKV + (size_t)(bn * 3 + 0) * TT * DD;
    const _Float16* kp = QKV + (size_t)(bn * 3 + 1) * TT * DD;
    const _Float16* vp = QKV + (size_t)(bn * 3 + 2) * TT * DD;
    const int b = bn / NN, n = bn - b * NN;

    #pragma unroll
    for (int p = 0; p < 3; ++p) {
        const int t = 8 * p + tl;
        const h4 qa = *(const h4*)(qp + t * DD + kh * 8);
        const h4 qb = *(const h4*)(qp + t * DD + kh * 8 + 4);
        float sc[TT];
        float mx = -3.0e38f;
        #pragma unroll
        for (int s = 8 * p; s < TT; ++s) {
            const h4 ka  = *(const h4*)(kp + s * DD + kh * 8);
            const h4 kb2 = *(const h4*)(kp + s * DD + kh * 8 + 4);
            float d = dot8(qa, qb, ka, kb2) * 0.35355339059327373f;  // 1/sqrt(8)
            d = (s >= t) ? d : -3.0e38f;                             // upper triangle
            sc[s] = d;
            mx = fmaxf(mx, d);
        }
        float sum = 0.f;
        #pragma unroll
        for (int s = 8 * p; s < TT; ++s) {
            const float e = __expf(sc[s] - mx);                      // masked -> 0
            sc[s] = e;
            sum += e;
        }
        f4 oa = {0.f, 0.f, 0.f, 0.f}, ob = {0.f, 0.f, 0.f, 0.f};
        #pragma unroll
        for (int s = 8 * p; s < TT; ++s) {
            const h4 va  = *(const h4*)(vp + s * DD + kh * 8);
            const h4 vb2 = *(const h4*)(vp + s * DD + kh * 8 + 4);
            const float pp = sc[s];
            const f4 vaf = {(float)va[0],  (float)va[1],  (float)va[2],  (float)va[3]};
            const f4 vbf = {(float)vb2[0], (float)vb2[1], (float)vb2[2], (float)vb2[3]};
            oa += pp * vaf;
            ob += pp * vbf;
        }
        const float inv = 1.f / sum;
        h4 ha, hb;
        #pragma unroll
        for (int i = 0; i < 4; ++i) {
            ha[i] = (_Float16)(oa[i] * inv);
            hb[i] = (_Float16)(ob[i] * inv);
        }
        _Float16* op = ATT + ((size_t)(b * TT + t) * NN + n) * DD + kh * 8;
        *(h4*)op       = ha;
        *(h4*)(op + 4) = hb;
    }
}

// ================= K3: FF1 + FF2 fused GEMM =================
__global__ __launch_bounds__(256) void ff_kernel(
    const _Float16* __restrict__ ATT, const _Float16* __restrict__ Wt,
    const float* __restrict__ bf1, const float* __restrict__ bf2,
    float* __restrict__ Out)
{
    __shared__ _Float16 hbuf[4][16 * HS];     // per-wave slice, no barriers
    const int lane = threadIdx.x & 63, w = threadIdx.x >> 6;
    const int lr = lane & 15, lg = lane >> 4;
    const int mbase = (blockIdx.x * 4 + w) * 16;
    const int m = mbase + lr;

    h4 a[4];
    const _Float16* ap = ATT + (size_t)m * DD;
    #pragma unroll
    for (int kt = 0; kt < 4; ++kt) a[kt] = *(const h4*)(ap + 16 * kt + 4 * lg);

    _Float16* hb = hbuf[w];

    // FF1: h = relu(att @ Wf1 + bf1) -> LDS
    {
        const _Float16* w1 = Wt + 3 * 4096;
        #pragma unroll
        for (int nt = 0; nt < 4; ++nt) {
            h4 bfr[4];
            const _Float16* wp = w1 + (16 * nt + lr) * 64 + 4 * lg;
            #pragma unroll
            for (int kt = 0; kt < 4; ++kt) bfr[kt] = *(const h4*)(wp + 16 * kt);
            f4 acc = *(const f4*)(bf1 + 16 * nt + 4 * lg);
            #pragma unroll
            for (int kt = 0; kt < 4; ++kt)
                acc = __builtin_amdgcn_mfma_f32_16x16x16f16(bfr[kt], a[kt], acc, 0, 0, 0);
            h4 o;
            #pragma unroll
            for (int i = 0; i < 4; ++i) o[i] = (_Float16)fmaxf(acc[i], 0.f);
            *(h4*)(hb + lr * HS + 16 * nt + 4 * lg) = o;   // h[row lr][cols 16nt+4lg..]
        }
    }

    // FF2: y = h @ Wf2 + bf2 -> global (f4, fully coalesced)
    {
        h4 a2[4];
        #pragma unroll
        for (int kt = 0; kt < 4; ++kt)
            a2[kt] = *(const h4*)(hb + lr * HS + 16 * kt + 4 * lg);
        const _Float16* w2 = Wt + 4 * 4096;
        #pragma unroll
        for (int nt = 0; nt < 4; ++nt) {
            h4 bfr[4];
            const _Float16* wp = w2 + (16 * nt + lr) * 64 + 4 * lg;
            #pragma unroll
            for (int kt = 0; kt < 4; ++kt) bfr[kt] = *(const h4*)(wp + 16 * kt);
            f4 acc = *(const f4*)(bf2 + 16 * nt + 4 * lg);
            #pragma unroll
            for (int kt = 0; kt < 4; ++kt)
                acc = __builtin_amdgcn_mfma_f32_16x16x16f16(bfr[kt], a2[kt], acc, 0, 0, 0);
            *(f4*)(Out + (size_t)m * DD + 16 * nt + 4 * lg) = acc;
        }
    }
}

// ================= fallback: round-3 fused wave kernel (known-good) =================
__global__ __launch_bounds__(128) void ta_wave_kernel(
    const float* __restrict__ X, const _Float16* __restrict__ Wt,
    const float* __restrict__ bq, const float* __restrict__ bk,
    const float* __restrict__ bv, const float* __restrict__ bf1,
    const float* __restrict__ bf2, float* __restrict__ Out)
{
    const int wid  = threadIdx.x >> 6;
    const int lane = threadIdx.x & 63;
    const int gw = blockIdx.x * 2 + wid;
    const int b = gw / NN, n = gw - b * NN;
    const int lr = lane & 15, lg = lane >> 4;

    __shared__ _Float16 qsh[2][TT * RSH];
    __shared__ _Float16 ksh[2][TT * RSH];
    __shared__ float    vsh[2][TT * RSF];
    _Float16* q = qsh[wid];
    _Float16* k = ksh[wid];
    float*    v = vsh[wid];

    const size_t xbase = (((size_t)b * TT) * NN + n) * DD;

    h4 a[2][4];
    #pragma unroll
    for (int mt = 0; mt < 2; ++mt) {
        const int row = mt * 16 + lr;
        const bool ok = row < TT;
        const float* xp = X + xbase + (size_t)row * (NN * DD);
        #pragma unroll
        for (int kt = 0; kt < 4; ++kt) {
            f4 x = {0.f, 0.f, 0.f, 0.f};
            if (ok) x = *(const f4*)(xp + kt * 16 + lg * 4);
            h4 h;
            h[0] = (_Float16)x[0]; h[1] = (_Float16)x[1];
            h[2] = (_Float16)x[2]; h[3] = (_Float16)x[3];
            a[mt][kt] = h;
        }
    }

#define MATMUL_NT(WOFF, BIASP, STORE)                                            \
    {                                                                            \
        _Pragma("unroll")                                                        \
        for (int nt = 0; nt < 4; ++nt) {                                         \
            const int col = 16 * nt + lr;                                        \
            const _Float16* wp = Wt + (WOFF) + col * 64 + lg * 4;                \
            h4 bfr[4];                                                           \
            _Pragma("unroll")                                                    \
            for (int kt = 0; kt < 4; ++kt) bfr[kt] = *(const h4*)(wp + kt * 16); \
            const float bb = (BIASP)[col];                                       \
            f4 acc0 = {bb, bb, bb, bb};                                          \
            f4 acc1 = acc0;                                                      \
            _Pragma("unroll")                                                    \
            for (int kt = 0; kt < 4; ++kt) {                                     \
                acc0 = __builtin_amdgcn_mfma_f32_16x16x16f16(a[0][kt], bfr[kt], acc0, 0, 0, 0); \
                acc1 = __builtin_amdgcn_mfma_f32_16x16x16f16(a[1][kt], bfr[kt], acc1, 0, 0, 0); \
            }                                                                    \
            _Pragma("unroll")                                                    \
            for (int r = 0; r < 4; ++r) {                                        \
                const int row0 = 4 * lg + r;                                     \
                const int row1 = 16 + row0;                                      \
                STORE(row0, col, acc0[r]);                                       \
                if (row1 < TT) STORE(row1, col, acc1[r]);                        \
            }                                                                    \
        }                                                                        \
    }

#define STQ(rr, cc, vv) q[(rr) * RSH + (cc)] = (_Float16)fmaxf((vv), 0.f)
#define STK(rr, cc, vv) k[(rr) * RSH + (cc)] = (_Float16)fmaxf((vv), 0.f)
#define STV(rr, cc, vv) v[(rr) * RSF + (cc)] = fmaxf((vv), 0.f)
#define STH(rr, cc, vv) k[(rr) * RSH + (cc)] = (_Float16)fmaxf((vv), 0.f)
#define STO(rr, cc, vv) Out[xbase + (size_t)(rr) * (NN * DD) + (cc)] = (vv)

#define LOAD_AFRAG(SRC)                                                          \
    {                                                                            \
        _Pragma("unroll")                                                        \
        for (int mt = 0; mt < 2; ++mt) {                                         \
            const int row = 16 * mt + lr;                                        \
            _Pragma("unroll")                                                    \
            for (int kt = 0; kt < 4; ++kt) {                                     \
                h4 tmpf = {(_Float16)0, (_Float16)0, (_Float16)0, (_Float16)0};  \
                if (row < TT) tmpf = *(const h4*)&(SRC)[row * RSH + kt * 16 + lg * 4]; \
                a[mt][kt] = tmpf;                                                \
            }                                                                    \
        }                                                                        \
    }

    MATMUL_NT(0 * 4096, bq, STQ)
    MATMUL_NT(1 * 4096, bk, STK)
    MATMUL_NT(2 * 4096, bv, STV)

    {
        const int kh = lane & 7;
        const int tl = lane >> 3;
        #pragma unroll
        for (int p = 0; p < 3; ++p) {
            const int t = 8 * p + tl;
            const h4 qa = *(const h4*)&q[t * RSH + kh * 8];
            const h4 qb = *(const h4*)&q[t * RSH + kh * 8 + 4];
            float sc[TT];
            float mx = -3.0e38f;
            #pragma unroll
            for (int s = 8 * p; s < TT; ++s) {
                const h4 ka = *(const h4*)&k[s * RSH + kh * 8];
                const h4 kb = *(const h4*)&k[s * RSH + kh * 8 + 4];
                float d = dot8(qa, qb, ka, kb) * 0.35355339059327373f;
                d = (s >= t) ? d : -3.0e38f;
                sc[s] = d;
                mx = fmaxf(mx, d);
            }
            float sum = 0.f;
            #pragma unroll
            for (int s = 8 * p; s < TT; ++s) {
                const float e = __expf(sc[s] - mx);
                sc[s] = e;
                sum += e;
            }
            f4 oa = {0.f, 0.f, 0.f, 0.f}, ob = {0.f, 0.f, 0.f, 0.f};
            #pragma unroll
            for (int s = 8 * p; s < TT; ++s) {
                const f4 va = *(const f4*)&v[s * RSF + kh * 8];
                const f4 vb = *(const f4*)&v[s * RSF + kh * 8 + 4];
                const float pp = sc[s];
                oa += pp * va;
                ob += pp * vb;
            }
            const float inv = 1.f / sum;
            h4 ha, hb;
            #pragma unroll
            for (int i = 0; i < 4; ++i) {
                ha[i] = (_Float16)(oa[i] * inv);
                hb[i] = (_Float16)(ob[i] * inv);
            }
            *(h4*)&q[t * RSH + kh * 8]     = ha;
            *(h4*)&q[t * RSH + kh * 8 + 4] = hb;
        }
    }

    LOAD_AFRAG(q)
    MATMUL_NT(3 * 4096, bf1, STH)
    LOAD_AFRAG(k)
    MATMUL_NT(4 * 4096, bf2, STO)
}

extern "C" void kernel_launch(void* const* d_in, const int* in_sizes, int n_in,
                              void* d_out, int out_size, void* d_ws, size_t ws_size,
                              hipStream_t stream) {
    const float* X   = (const float*)d_in[0];
    // d_in[1] = STE (unused by the reference)
    const float* Wq  = (const float*)d_in[2];
    const float* bq  = (const float*)d_in[3];
    const float* Wk  = (const float*)d_in[4];
    const float* bk  = (const float*)d_in[5];
    const float* Wv  = (const float*)d_in[6];
    const float* bv  = (const float*)d_in[7];
    const float* Wf1 = (const float*)d_in[8];
    const float* bf1 = (const float*)d_in[9];
    const float* Wf2 = (const float*)d_in[10];
    const float* bf2 = (const float*)d_in[11];
    float* Out = (float*)d_out;

    _Float16* Wt = (_Float16*)d_ws;                       // 40 KB
    const size_t QKV_OFF   = 65536;                       // bytes
    const size_t QKV_BYTES = (size_t)BNCNT * 3 * TT * DD * 2;   // 95,846,400
    const size_t ATT_OFF   = QKV_OFF + QKV_BYTES;
    const size_t ATT_BYTES = (size_t)MROWS * DD * 2;            // 31,948,800
    const size_t NEED      = ATT_OFF + ATT_BYTES;

    prep_w_kernel<<<5, 256, 0, stream>>>(Wq, Wk, Wv, Wf1, Wf2, Wt);

    if (ws_size >= NEED) {
        _Float16* QKV = (_Float16*)((char*)d_ws + QKV_OFF);
        _Float16* ATT = (_Float16*)((char*)d_ws + ATT_OFF);
        qkv_kernel <<<MROWS / 64, 256, 0, stream>>>(X, Wt, bq, bk, bv, QKV);
        attn_kernel<<<BNCNT / 4,  256, 0, stream>>>(QKV, ATT);
        ff_kernel  <<<MROWS / 64, 256, 0, stream>>>(ATT, Wt, bf1, bf2, Out);
    } else {
        ta_wave_kernel<<<(BB * NN) / 2, 128, 0, stream>>>(X, Wt, bq, bk, bv, bf1, bf2, Out);
    }
}

// Round 5
// 335.783 us; speedup vs baseline: 1.1480x; 1.1480x over previous
//
#include <hip/hip_runtime.h>
#include <hip/hip_bf16.h>

#define BB 32
#define TT 24
#define NN 325
#define DD 64
#define MROWS (BB * TT * NN)   // 249600 flat (b,t,n) rows
#define BNCNT (BB * NN)        // 10400 (b,n) problems
#define SR    (NN * DD)        // 20800: element stride between consecutive t rows
#define RSH 72                 // f16 LDS row stride in halves (144 B)
#define RSF 68                 // fallback: f32 LDS row stride (floats)

typedef _Float16 h4 __attribute__((ext_vector_type(4)));
typedef _Float16 h2 __attribute__((ext_vector_type(2)));
typedef float    f4 __attribute__((ext_vector_type(4)));

// ---------------- prep: W (f32, [k][col]) -> Wt (f16, [col][k]) ----------------
__global__ void prep_w_kernel(const float* __restrict__ Wq, const float* __restrict__ Wk,
                              const float* __restrict__ Wv, const float* __restrict__ Wf1,
                              const float* __restrict__ Wf2, _Float16* __restrict__ Wt)
{
    __shared__ float tile[64][65];
    const float* W;
    switch (blockIdx.x) {
        case 0: W = Wq; break;
        case 1: W = Wk; break;
        case 2: W = Wv; break;
        case 3: W = Wf1; break;
        default: W = Wf2; break;
    }
    const int tid = threadIdx.x;
    const int g = tid >> 6, c = tid & 63;
    #pragma unroll
    for (int p = 0; p < 16; ++p) {
        const int row = p * 4 + g;
        tile[row][c] = W[row * 64 + c];
    }
    __syncthreads();
    _Float16* dst = Wt + blockIdx.x * 4096;
    #pragma unroll
    for (int p = 0; p < 16; ++p) {
        const int col = p * 4 + g;
        dst[col * 64 + c] = (_Float16)tile[c][col];  // Wt[col][k]
    }
}

__device__ inline float dot8(h4 qa, h4 qb, h4 ka, h4 kb) {
#if __has_builtin(__builtin_amdgcn_fdot2)
    h2 qa0 = {qa[0], qa[1]}, qa1 = {qa[2], qa[3]};
    h2 qb0 = {qb[0], qb[1]}, qb1 = {qb[2], qb[3]};
    h2 ka0 = {ka[0], ka[1]}, ka1 = {ka[2], ka[3]};
    h2 kb0 = {kb[0], kb[1]}, kb1 = {kb[2], kb[3]};
    float d = __builtin_amdgcn_fdot2(qa0, ka0, 0.f, false);
    d = __builtin_amdgcn_fdot2(qa1, ka1, d, false);
    d = __builtin_amdgcn_fdot2(qb0, kb0, d, false);
    d = __builtin_amdgcn_fdot2(qb1, kb1, d, false);
    return d;
#else
    return (float)qa[0]*(float)ka[0] + (float)qa[1]*(float)ka[1]
         + (float)qa[2]*(float)ka[2] + (float)qa[3]*(float)ka[3]
         + (float)qb[0]*(float)kb[0] + (float)qb[1]*(float)kb[1]
         + (float)qb[2]*(float)kb[2] + (float)qb[3]*(float)kb[3];
#endif
}

// ================= K1: QKV projection GEMM, m-order outputs =================
// X [249600][64] f32 -> Q,K,V each [249600][64] f16 (same flat row order).
// Swapped-operand MFMA: lane(lr,lg) holds out[row mbase+lr][cols 16nt+4lg+q].
// Wave writes a contiguous 16-row x 128 B region per buffer (line-granule).
__global__ __launch_bounds__(256) void qkv_kernel(
    const float* __restrict__ X, const _Float16* __restrict__ Wt,
    const float* __restrict__ bq, const float* __restrict__ bk,
    const float* __restrict__ bv, _Float16* __restrict__ QKV)
{
    const int lane = threadIdx.x & 63, w = threadIdx.x >> 6;
    const int lr = lane & 15, lg = lane >> 4;
    const int mbase = (blockIdx.x * 4 + w) * 16;
    const int m = mbase + lr;                 // < 249600 exactly (3900*4*16)

    h4 a[4];
    const float* xp = X + (size_t)m * DD;
    #pragma unroll
    for (int kt = 0; kt < 4; ++kt) {
        const f4 x = *(const f4*)(xp + kt * 16 + lg * 4);
        h4 h; h[0] = (_Float16)x[0]; h[1] = (_Float16)x[1];
        h[2] = (_Float16)x[2]; h[3] = (_Float16)x[3];
        a[kt] = h;
    }

    #pragma unroll
    for (int sep = 0; sep < 3; ++sep) {
        const float* bias = (sep == 0) ? bq : (sep == 1) ? bk : bv;
        const _Float16* wsep = Wt + sep * 4096;
        _Float16* osep = QKV + (size_t)sep * (MROWS * DD) + (size_t)m * DD;
        #pragma unroll
        for (int nt = 0; nt < 4; ++nt) {
            h4 bfr[4];
            const _Float16* wp = wsep + (16 * nt + lr) * 64 + 4 * lg;
            #pragma unroll
            for (int kt = 0; kt < 4; ++kt) bfr[kt] = *(const h4*)(wp + 16 * kt);
            f4 acc = *(const f4*)(bias + 16 * nt + 4 * lg);
            #pragma unroll
            for (int kt = 0; kt < 4; ++kt)
                acc = __builtin_amdgcn_mfma_f32_16x16x16f16(bfr[kt], a[kt], acc, 0, 0, 0);
            h4 o;
            #pragma unroll
            for (int i = 0; i < 4; ++i) o[i] = (_Float16)fmaxf(acc[i], 0.f);
            *(h4*)(osep + 16 * nt + 4 * lg) = o;
        }
    }
}

// ================= K2: attention + FF1 + FF2, one wave per (b,n) =================
// q/k/v read from m-order buffers (full 128B rows, L2/L3-served). No barriers.
// Tiny per-wave LDS tile only for the attention-out -> MFMA-fragment shuffle.
__global__ __launch_bounds__(256) void attnff_kernel(
    const _Float16* __restrict__ QKV, const _Float16* __restrict__ Wt,
    const float* __restrict__ bf1, const float* __restrict__ bf2,
    float* __restrict__ Out)
{
    __shared__ _Float16 tsh[4][TT * RSH];    // 13.8 KB/block, wave-private slices
    const int lane = threadIdx.x & 63, w = threadIdx.x >> 6;
    const int bn = blockIdx.x * 4 + w;       // < 10400 exactly (2600*4)
    const int b = bn / NN, n = bn - b * NN;
    _Float16* tile = tsh[w];

    const _Float16* Qb = QKV + (size_t)(b * (TT * NN) + n) * DD;
    const _Float16* Kb = Qb + (size_t)(MROWS * DD);
    const _Float16* Vb = Kb + (size_t)(MROWS * DD);

    // ---- attention: 3 passes, lane = (kh = lane&7, tl = lane>>3), t = 8p + tl ----
    {
        const int kh = lane & 7;
        const int tl = lane >> 3;
        #pragma unroll
        for (int p = 0; p < 3; ++p) {
            const int t = 8 * p + tl;
            const h4 qa = *(const h4*)(Qb + (size_t)t * SR + kh * 8);
            const h4 qb = *(const h4*)(Qb + (size_t)t * SR + kh * 8 + 4);
            float sc[TT];
            float mx = -3.0e38f;
            #pragma unroll
            for (int s = 8 * p; s < TT; ++s) {
                const h4 ka  = *(const h4*)(Kb + (size_t)s * SR + kh * 8);
                const h4 kb2 = *(const h4*)(Kb + (size_t)s * SR + kh * 8 + 4);
                float d = dot8(qa, qb, ka, kb2) * 0.35355339059327373f;  // 1/sqrt(8)
                d = (s >= t) ? d : -3.0e38f;                             // upper triangle
                sc[s] = d;
                mx = fmaxf(mx, d);
            }
            float sum = 0.f;
            #pragma unroll
            for (int s = 8 * p; s < TT; ++s) {
                const float e = __expf(sc[s] - mx);                      // masked -> 0
                sc[s] = e;
                sum += e;
            }
            f4 oa = {0.f, 0.f, 0.f, 0.f}, ob = {0.f, 0.f, 0.f, 0.f};
            #pragma unroll
            for (int s = 8 * p; s < TT; ++s) {
                const h4 va  = *(const h4*)(Vb + (size_t)s * SR + kh * 8);
                const h4 vb2 = *(const h4*)(Vb + (size_t)s * SR + kh * 8 + 4);
                const float pp = sc[s];
                const f4 vaf = {(float)va[0],  (float)va[1],  (float)va[2],  (float)va[3]};
                const f4 vbf = {(float)vb2[0], (float)vb2[1], (float)vb2[2], (float)vb2[3]};
                oa += pp * vaf;
                ob += pp * vbf;
            }
            const float inv = 1.f / sum;
            h4 ha, hb;
            #pragma unroll
            for (int i = 0; i < 4; ++i) {
                ha[i] = (_Float16)(oa[i] * inv);
                hb[i] = (_Float16)(ob[i] * inv);
            }
            *(h4*)&tile[t * RSH + kh * 8]     = ha;
            *(h4*)&tile[t * RSH + kh * 8 + 4] = hb;
        }
    }

    // ---- FF1 + FF2 via MFMA (within-wave LDS ordering via lgkmcnt, no barriers) ----
    const int lr = lane & 15, lg = lane >> 4;
    h4 a0[4], a1[4];

    #pragma unroll
    for (int kt = 0; kt < 4; ++kt) {
        a0[kt] = *(const h4*)&tile[lr * RSH + kt * 16 + lg * 4];
        h4 z = {(_Float16)0, (_Float16)0, (_Float16)0, (_Float16)0};
        if (16 + lr < TT) z = *(const h4*)&tile[(16 + lr) * RSH + kt * 16 + lg * 4];
        a1[kt] = z;
    }

    // FF1: h = relu(att @ Wf1 + bf1) -> back into tile
    #pragma unroll
    for (int nt = 0; nt < 4; ++nt) {
        const int col = 16 * nt + lr;
        const _Float16* wp = Wt + 3 * 4096 + col * 64 + 4 * lg;
        h4 bfr[4];
        #pragma unroll
        for (int kt = 0; kt < 4; ++kt) bfr[kt] = *(const h4*)(wp + 16 * kt);
        const float bb = bf1[col];
        f4 acc0 = {bb, bb, bb, bb};
        f4 acc1 = acc0;
        #pragma unroll
        for (int kt = 0; kt < 4; ++kt) {
            acc0 = __builtin_amdgcn_mfma_f32_16x16x16f16(a0[kt], bfr[kt], acc0, 0, 0, 0);
            acc1 = __builtin_amdgcn_mfma_f32_16x16x16f16(a1[kt], bfr[kt], acc1, 0, 0, 0);
        }
        #pragma unroll
        for (int r = 0; r < 4; ++r) {
            const int row0 = 4 * lg + r;
            tile[row0 * RSH + col] = (_Float16)fmaxf(acc0[r], 0.f);
            const int row1 = 16 + row0;
            if (row1 < TT) tile[row1 * RSH + col] = (_Float16)fmaxf(acc1[r], 0.f);
        }
    }

    // FF2: y = h @ Wf2 + bf2 -> Out (f32, 64B chunks per row)
    #pragma unroll
    for (int kt = 0; kt < 4; ++kt) {
        a0[kt] = *(const h4*)&tile[lr * RSH + kt * 16 + lg * 4];
        h4 z = {(_Float16)0, (_Float16)0, (_Float16)0, (_Float16)0};
        if (16 + lr < TT) z = *(const h4*)&tile[(16 + lr) * RSH + kt * 16 + lg * 4];
        a1[kt] = z;
    }
    const size_t obase = (size_t)(b * (TT * NN) + n) * DD;
    #pragma unroll
    for (int nt = 0; nt < 4; ++nt) {
        const int col = 16 * nt + lr;
        const _Float16* wp = Wt + 4 * 4096 + col * 64 + 4 * lg;
        h4 bfr[4];
        #pragma unroll
        for (int kt = 0; kt < 4; ++kt) bfr[kt] = *(const h4*)(wp + 16 * kt);
        const float bb = bf2[col];
        f4 acc0 = {bb, bb, bb, bb};
        f4 acc1 = acc0;
        #pragma unroll
        for (int kt = 0; kt < 4; ++kt) {
            acc0 = __builtin_amdgcn_mfma_f32_16x16x16f16(a0[kt], bfr[kt], acc0, 0, 0, 0);
            acc1 = __builtin_amdgcn_mfma_f32_16x16x16f16(a1[kt], bfr[kt], acc1, 0, 0, 0);
        }
        #pragma unroll
        for (int r = 0; r < 4; ++r) {
            const int row0 = 4 * lg + r;
            Out[obase + (size_t)row0 * SR + col] = acc0[r];
            const int row1 = 16 + row0;
            if (row1 < TT) Out[obase + (size_t)row1 * SR + col] = acc1[r];
        }
    }
}

// ================= fallback: round-3 fused wave kernel (known-good) =================
__global__ __launch_bounds__(128) void ta_wave_kernel(
    const float* __restrict__ X, const _Float16* __restrict__ Wt,
    const float* __restrict__ bq, const float* __restrict__ bk,
    const float* __restrict__ bv, const float* __restrict__ bf1,
    const float* __restrict__ bf2, float* __restrict__ Out)
{
    const int wid  = threadIdx.x >> 6;
    const int lane = threadIdx.x & 63;
    const int gw = blockIdx.x * 2 + wid;
    const int b = gw / NN, n = gw - b * NN;
    const int lr = lane & 15, lg = lane >> 4;

    __shared__ _Float16 qsh[2][TT * RSH];
    __shared__ _Float16 ksh[2][TT * RSH];
    __shared__ float    vsh[2][TT * RSF];
    _Float16* q = qsh[wid];
    _Float16* k = ksh[wid];
    float*    v = vsh[wid];

    const size_t xbase = (((size_t)b * TT) * NN + n) * DD;

    h4 a[2][4];
    #pragma unroll
    for (int mt = 0; mt < 2; ++mt) {
        const int row = mt * 16 + lr;
        const bool ok = row < TT;
        const float* xp = X + xbase + (size_t)row * (NN * DD);
        #pragma unroll
        for (int kt = 0; kt < 4; ++kt) {
            f4 x = {0.f, 0.f, 0.f, 0.f};
            if (ok) x = *(const f4*)(xp + kt * 16 + lg * 4);
            h4 h;
            h[0] = (_Float16)x[0]; h[1] = (_Float16)x[1];
            h[2] = (_Float16)x[2]; h[3] = (_Float16)x[3];
            a[mt][kt] = h;
        }
    }

#define MATMUL_NT(WOFF, BIASP, STORE)                                            \
    {                                                                            \
        _Pragma("unroll")                                                        \
        for (int nt = 0; nt < 4; ++nt) {                                         \
            const int col = 16 * nt + lr;                                        \
            const _Float16* wp = Wt + (WOFF) + col * 64 + lg * 4;                \
            h4 bfr[4];                                                           \
            _Pragma("unroll")                                                    \
            for (int kt = 0; kt < 4; ++kt) bfr[kt] = *(const h4*)(wp + kt * 16); \
            const float bb = (BIASP)[col];                                       \
            f4 acc0 = {bb, bb, bb, bb};                                          \
            f4 acc1 = acc0;                                                      \
            _Pragma("unroll")                                                    \
            for (int kt = 0; kt < 4; ++kt) {                                     \
                acc0 = __builtin_amdgcn_mfma_f32_16x16x16f16(a[0][kt], bfr[kt], acc0, 0, 0, 0); \
                acc1 = __builtin_amdgcn_mfma_f32_16x16x16f16(a[1][kt], bfr[kt], acc1, 0, 0, 0); \
            }                                                                    \
            _Pragma("unroll")                                                    \
            for (int r = 0; r < 4; ++r) {                                        \
                const int row0 = 4 * lg + r;                                     \
                const int row1 = 16 + row0;                                      \
                STORE(row0, col, acc0[r]);                                       \
                if (row1 < TT) STORE(row1, col, acc1[r]);                        \
            }                                                                    \
        }                                                                        \
    }

#define STQ(rr, cc, vv) q[(rr) * RSH + (cc)] = (_Float16)fmaxf((vv), 0.f)
#define STK(rr, cc, vv) k[(rr) * RSH + (cc)] = (_Float16)fmaxf((vv), 0.f)
#define STV(rr, cc, vv) v[(rr) * RSF + (cc)] = fmaxf((vv), 0.f)
#define STH(rr, cc, vv) k[(rr) * RSH + (cc)] = (_Float16)fmaxf((vv), 0.f)
#define STO(rr, cc, vv) Out[xbase + (size_t)(rr) * (NN * DD) + (cc)] = (vv)

#define LOAD_AFRAG(SRC)                                                          \
    {                                                                            \
        _Pragma("unroll")                                                        \
        for (int mt = 0; mt < 2; ++mt) {                                         \
            const int row = 16 * mt + lr;                                        \
            _Pragma("unroll")                                                    \
            for (int kt = 0; kt < 4; ++kt) {                                     \
                h4 tmpf = {(_Float16)0, (_Float16)0, (_Float16)0, (_Float16)0};  \
                if (row < TT) tmpf = *(const h4*)&(SRC)[row * RSH + kt * 16 + lg * 4]; \
                a[mt][kt] = tmpf;                                                \
            }                                                                    \
        }                                                                        \
    }

    MATMUL_NT(0 * 4096, bq, STQ)
    MATMUL_NT(1 * 4096, bk, STK)
    MATMUL_NT(2 * 4096, bv, STV)

    {
        const int kh = lane & 7;
        const int tl = lane >> 3;
        #pragma unroll
        for (int p = 0; p < 3; ++p) {
            const int t = 8 * p + tl;
            const h4 qa = *(const h4*)&q[t * RSH + kh * 8];
            const h4 qb = *(const h4*)&q[t * RSH + kh * 8 + 4];
            float sc[TT];
            float mx = -3.0e38f;
            #pragma unroll
            for (int s = 8 * p; s < TT; ++s) {
                const h4 ka = *(const h4*)&k[s * RSH + kh * 8];
                const h4 kb = *(const h4*)&k[s * RSH + kh * 8 + 4];
                float d = dot8(qa, qb, ka, kb) * 0.35355339059327373f;
                d = (s >= t) ? d : -3.0e38f;
                sc[s] = d;
                mx = fmaxf(mx, d);
            }
            float sum = 0.f;
            #pragma unroll
            for (int s = 8 * p; s < TT; ++s) {
                const float e = __expf(sc[s] - mx);
                sc[s] = e;
                sum += e;
            }
            f4 oa = {0.f, 0.f, 0.f, 0.f}, ob = {0.f, 0.f, 0.f, 0.f};
            #pragma unroll
            for (int s = 8 * p; s < TT; ++s) {
                const f4 va = *(const f4*)&v[s * RSF + kh * 8];
                const f4 vb = *(const f4*)&v[s * RSF + kh * 8 + 4];
                const float pp = sc[s];
                oa += pp * va;
                ob += pp * vb;
            }
            const float inv = 1.f / sum;
            h4 ha, hb;
            #pragma unroll
            for (int i = 0; i < 4; ++i) {
                ha[i] = (_Float16)(oa[i] * inv);
                hb[i] = (_Float16)(ob[i] * inv);
            }
            *(h4*)&q[t * RSH + kh * 8]     = ha;
            *(h4*)&q[t * RSH + kh * 8 + 4] = hb;
        }
    }

    LOAD_AFRAG(q)
    MATMUL_NT(3 * 4096, bf1, STH)
    LOAD_AFRAG(k)
    MATMUL_NT(4 * 4096, bf2, STO)
}

extern "C" void kernel_launch(void* const* d_in, const int* in_sizes, int n_in,
                              void* d_out, int out_size, void* d_ws, size_t ws_size,
                              hipStream_t stream) {
    const float* X   = (const float*)d_in[0];
    // d_in[1] = STE (unused by the reference)
    const float* Wq  = (const float*)d_in[2];
    const float* bq  = (const float*)d_in[3];
    const float* Wk  = (const float*)d_in[4];
    const float* bk  = (const float*)d_in[5];
    const float* Wv  = (const float*)d_in[6];
    const float* bv  = (const float*)d_in[7];
    const float* Wf1 = (const float*)d_in[8];
    const float* bf1 = (const float*)d_in[9];
    const float* Wf2 = (const float*)d_in[10];
    const float* bf2 = (const float*)d_in[11];
    float* Out = (float*)d_out;

    _Float16* Wt = (_Float16*)d_ws;                            // 40 KB
    const size_t QKV_OFF   = 65536;                            // bytes
    const size_t QKV_BYTES = (size_t)3 * MROWS * DD * 2;       // 95,846,400
    const size_t NEED      = QKV_OFF + QKV_BYTES;

    prep_w_kernel<<<5, 256, 0, stream>>>(Wq, Wk, Wv, Wf1, Wf2, Wt);

    if (ws_size >= NEED) {
        _Float16* QKV = (_Float16*)((char*)d_ws + QKV_OFF);
        qkv_kernel   <<<MROWS / 64, 256, 0, stream>>>(X, Wt, bq, bk, bv, QKV);
        attnff_kernel<<<BNCNT / 4,  256, 0, stream>>>(QKV, Wt, bf1, bf2, Out);
    } else {
        ta_wave_kernel<<<(BB * NN) / 2, 128, 0, stream>>>(X, Wt, bq, bk, bv, bf1, bf2, Out);
    }
}